// Round 11
// baseline (258.167 us; speedup 1.0000x reference)
//
#include <hip/hip_runtime.h>
#include <hip/hip_bf16.h>
#include <stdint.h>

#define IMG_H 96
#define IMG_W 96
#define IMG_C 3
#define HO    90                 // 96-7+1
#define NPAT  8100               // 90*90
#define NPAD  8192
#define DDIM  147                // 3*7*7
#define KPAD  160                // padded K (5 chunks of 32)
#define NCHK  5
#define BATCH 4
#define TILE  128
#define NT    (NPAD / TILE)      // 64 stream tiles
#define ALPHA 0.05f

typedef __attribute__((ext_vector_type(8))) short short8;
typedef __attribute__((ext_vector_type(4))) float f32x4;

__device__ __forceinline__ void async16(const void* g, void* l) {
    __builtin_amdgcn_global_load_lds(
        (const __attribute__((address_space(1))) unsigned int*)g,
        (__attribute__((address_space(3))) unsigned int*)l,
        16, 0, 0);
}

// ---------- patch extraction + squared norms (+ out zero) ----------
__global__ __launch_bounds__(256) void extract_patches(
    const float* __restrict__ img,          // [B][3][96][96]
    __hip_bfloat16* __restrict__ pat,       // [B][NPAD][KPAD]
    float* __restrict__ nrm,                // [B][NPAD]
    float* __restrict__ outzero)            // may be null
{
    int wid  = threadIdx.x >> 6;
    int lane = threadIdx.x & 63;
    int pidx = blockIdx.x * 4 + wid;        // 0..8191
    int b    = blockIdx.y;
    if (pidx >= NPAD) return;
    if (outzero && blockIdx.x == 0 && blockIdx.y == 0 && threadIdx.x == 0)
        outzero[0] = 0.f;
    const float* im = img + (size_t)b * (IMG_C * IMG_H * IMG_W);
    __hip_bfloat16* pp = pat + ((size_t)b * NPAD + pidx) * KPAD;
    int r = pidx / HO, c = pidx - r * HO;
    bool valid = pidx < NPAT;
    float ss = 0.f;
    for (int d = lane; d < KPAD; d += 64) {
        float v = 0.f;
        if (valid && d < DDIM) {
            int ch  = d / 49;
            int rem = d - ch * 49;
            int pr  = rem / 7, pc = rem - pr * 7;
            v = im[ch * (IMG_H * IMG_W) + (r + pr) * IMG_W + (c + pc)];
        }
        pp[d] = __float2bfloat16(v);
        ss += v * v;
    }
    for (int s = 32; s; s >>= 1) ss += __shfl_down(ss, s);
    if (lane == 0) nrm[(size_t)b * NPAD + pidx] = ss;
}

// ---------- prep: rms = invD/(row_min+a) (inf pads) fused with y2 -> float2 ----------
__global__ __launch_bounds__(256) void prep_rms(
    const float* __restrict__ row_min, const float* __restrict__ y2,
    float2* __restrict__ yr)
{
    int i = blockIdx.x * 256 + threadIdx.x;
    if (i < BATCH * NPAD) {
        int j = i & (NPAD - 1);
        float rm = row_min[i];
        float rr = (j < NPAT) ? (1.0f / (float)DDIM) / (rm + ALPHA)
                              : __builtin_inff();
        yr[i] = make_float2(y2[i], rr);
    }
}

// -------------------- panel-persistent fused GEMM passes --------------------
// 1024 threads = 16 waves = 4 waves/SIMD (2x R8's latency hiding).
// Panel (128 rows/cols) in registers: p_reg[5][4] per wave (wp half).
// Stream tiles double-buffered in LDS; waves 0-7 stage (5 async16 each),
// wave 8 stages smalls (ONE async16/lane: 64 lanes x 16B covers the row —
// R10's two-wave version raced and overflowed); one __syncthreads per tile.
// Wave layout: wp=wid>>3 (2 x 64 panel rows), ws=wid&7 (8 x 16 stream cols).
// PASS 1: row-min in regs -> plain store per row (no atomics).
// PASS 2: col-min in regs -> one atomicAdd partial per block.
template <int PASS>
__global__ __launch_bounds__(1024) void panel_pass(
    const __hip_bfloat16* __restrict__ Xp,   // [B][NPAD][KPAD]
    const __hip_bfloat16* __restrict__ Yp,   // [B][NPAD][KPAD]
    const float* __restrict__ x2,
    const float* __restrict__ y2,
    const float2* __restrict__ yr,           // PASS2: (y2, rms) pairs
    float* __restrict__ row_min,
    float* __restrict__ out)                 // PASS2 only
{
    __shared__ __align__(16) __hip_bfloat16 S[2][NCHK * TILE * 32]; // 2 x 40 KB
    __shared__ __align__(16) float  sm_a[2][TILE];    // PASS1: stream x2
    __shared__ __align__(16) float2 sm_yr[2][TILE];   // PASS2: stream (y2,rms)
    __shared__ __align__(16) float  pnl[TILE];        // panel: y2 (P1) / x2 (P2)
    __shared__ float red[8][TILE];                    // cross-wave reduce

    int blk = blockIdx.x;
    int bz  = blk & 3;               // image (XCD-locality under %8 rr)
    int tP  = blk >> 2;              // panel index 0..63
    int tid = threadIdx.x;
    int wid = tid >> 6, lane = tid & 63;
    int wp  = wid >> 3;              // panel half (2 x 64 rows)
    int ws  = wid & 7;               // stream group (8 x 16 cols)

    const __hip_bfloat16* Pbase =
        (PASS == 1 ? Yp : Xp) + ((size_t)bz * NPAD + tP * TILE) * KPAD;
    const __hip_bfloat16* Sbase =
        (PASS == 1 ? Xp : Yp) + (size_t)bz * NPAD * KPAD;
    const float* pnl_src = (PASS == 1 ? y2 : x2) + (size_t)bz * NPAD + tP * TILE;
    const float*  sma_src = x2 + (size_t)bz * NPAD;           // PASS1
    const float2* syr_src = yr + (size_t)bz * NPAD;           // PASS2

    // stage one 128x160 tile: waves 0-7, 5 async16/thread (inverse-swz source)
    auto stageS = [&](int buf, const __hip_bfloat16* gsrc) {
        if (wid < 8) {
            int row  = wid * 16 + (lane >> 2);
            int slog = (lane & 3) ^ ((row >> 1) & 3);
            const __hip_bfloat16* src = gsrc + (size_t)row * KPAD + slog * 8;
            __hip_bfloat16* dbase = &S[buf][wid * 512];
            for (int c = 0; c < NCHK; ++c)
                async16(src + c * 32, dbase + c * 4096);
        }
    };
    auto stage_small = [&](int buf, int t) {
        if (PASS == 1) {
            if (wid == 8 && lane < 32)       // 32 lanes x 4 floats = 128
                async16(sma_src + (size_t)t * TILE + lane * 4, &sm_a[buf][0]);
        } else {
            if (wid == 8)                    // 64 lanes x 2 float2 = 128
                async16(syr_src + (size_t)t * TILE + lane * 2, &sm_yr[buf][0]);
        }
    };

    // prologue: panel -> S1; tile0 -> S0; smalls; panel scalars
    stageS(1, Pbase);
    stageS(0, Sbase);
    stage_small(0, 0);
    if (wid == 9 && lane < 32) async16(pnl_src + lane * 4, &pnl[0]);
    __syncthreads();                 // drain: everything landed

    int fr    = lane & 15;
    int sread = ((lane >> 4) ^ ((lane >> 1) & 3)) * 8;  // swizzled 16B slot
    int prow  = wp * 64 + fr;
    int srow  = ws * 16 + fr;

    // panel fragments -> registers (20 ds_read_b128, once)
    short8 p_reg[NCHK][4];
#pragma unroll
    for (int c = 0; c < NCHK; ++c)
#pragma unroll
        for (int m = 0; m < 4; ++m)
            p_reg[c][m] =
                *(const short8*)&S[1][c * 4096 + (prow + m * 16) * 32 + sread];

    float xv[4];   // PASS2: own panel cols' x2
    if (PASS == 2)
#pragma unroll
        for (int nb = 0; nb < 4; ++nb) xv[nb] = pnl[wp * 64 + nb * 16 + fr];

    __syncthreads();   // lgkmcnt(0) drained: p_reg in regs before S1 reuse

    float runmin[PASS == 1 ? 16 : 4];
#pragma unroll
    for (int i = 0; i < (PASS == 1 ? 16 : 4); ++i)
        runmin[i] = __builtin_inff();

#pragma unroll 1
    for (int t = 0; t < NT; ++t) {
        int cur = t & 1;
        if (t + 1 < NT) {            // prefetch next tile (hidden under compute)
            stageS(cur ^ 1, Sbase + (size_t)(t + 1) * TILE * KPAD);
            stage_small(cur ^ 1, t + 1);
        }

        const __hip_bfloat16* Sc = &S[cur][0];

        f32x4 acc[4] = {};
#pragma unroll
        for (int c = 0; c < NCHK; ++c) {
            short8 s0 = *(const short8*)&Sc[c * 4096 + srow * 32 + sread];
            if (PASS == 1) {
#pragma unroll
                for (int m = 0; m < 4; ++m)
                    acc[m] = __builtin_amdgcn_mfma_f32_16x16x32_bf16(
                        p_reg[c][m], s0, acc[m], 0, 0, 0);
            } else {
#pragma unroll
                for (int nb = 0; nb < 4; ++nb)
                    acc[nb] = __builtin_amdgcn_mfma_f32_16x16x32_bf16(
                        s0, p_reg[c][nb], acc[nb], 0, 0, 0);
            }
        }

        if (PASS == 1) {
            int ic = ws * 16 + fr;
            float xx = sm_a[cur][ic];
            float xvn = (t * TILE + ic < NPAT) ? xx : __builtin_inff();
#pragma unroll
            for (int m = 0; m < 4; ++m)
#pragma unroll
                for (int reg = 0; reg < 4; ++reg)
                    runmin[m * 4 + reg] = fminf(runmin[m * 4 + reg],
                        fmaf(-2.0f, acc[m][reg], xvn));
        } else {
#pragma unroll
            for (int reg = 0; reg < 4; ++reg) {
                int jl = ws * 16 + (lane >> 4) * 4 + reg;
                float2 p = sm_yr[cur][jl];   // (y2, rms); rms=inf on pad rows
#pragma unroll
                for (int nb = 0; nb < 4; ++nb)
                    runmin[nb] = fminf(runmin[nb],
                        fmaf(-2.0f, acc[nb][reg], p.x + xv[nb]) * p.y);
            }
        }
        __syncthreads();             // drains prefetch + buffer handshake
    }

    if (PASS == 1) {
        // reduce over 16 stream cols (lane fr dim) -> cross-ws -> plain store
#pragma unroll
        for (int m = 0; m < 4; ++m)
#pragma unroll
            for (int reg = 0; reg < 4; ++reg) {
                float v = runmin[m * 4 + reg];
                for (int s = 1; s < 16; s <<= 1)
                    v = fminf(v, __shfl_xor(v, s));
                if ((lane & 15) == 0)
                    red[ws][wp * 64 + m * 16 + (lane >> 4) * 4 + reg] = v;
            }
        __syncthreads();
        if (tid < TILE) {
            float mv = red[0][tid];
#pragma unroll
            for (int w = 1; w < 8; ++w) mv = fminf(mv, red[w][tid]);
            row_min[(size_t)bz * NPAD + tP * TILE + tid] =
                fmaxf(pnl[tid] + mv, 0.f) * (1.0f / (float)DDIM);
        }
    } else {
        // reduce over stream rows -> cross-ws -> clamp/mask -> 1 atomic
#pragma unroll
        for (int nb = 0; nb < 4; ++nb) {
            float v = runmin[nb];
            v = fminf(v, __shfl_xor(v, 16));
            v = fminf(v, __shfl_xor(v, 32));
            if (lane < 16) red[ws][wp * 64 + nb * 16 + lane] = v;
        }
        __syncthreads();
        if (tid < TILE) {
            int gc = tP * TILE + tid;
            float cv = red[0][tid];
#pragma unroll
            for (int w = 1; w < 8; ++w) cv = fminf(cv, red[w][tid]);
            cv = fmaxf(cv, 0.f);                   // deferred clamp (monotone)
            red[0][tid] = (gc < NPAT) ? cv : 0.f;  // mask pad cols
        }
        __syncthreads();
        if (tid < 64) {
            float s = red[0][tid] + red[0][tid + 64];
            for (int o = 32; o; o >>= 1) s += __shfl_down(s, o);
            if (tid == 0)
                atomicAdd(out, s * (1.0f / (float)(BATCH * NPAT)));
        }
    }
}

extern "C" void kernel_launch(void* const* d_in, const int* in_sizes, int n_in,
                              void* d_out, int out_size, void* d_ws, size_t ws_size,
                              hipStream_t stream) {
    const float* x = (const float*)d_in[0];
    const float* y = (const float*)d_in[1];
    float* out = (float*)d_out;

    char* ws = (char*)d_ws;
    size_t patSz = (size_t)BATCH * NPAD * KPAD * sizeof(__hip_bfloat16); // 10.5 MB
    __hip_bfloat16* Xp = (__hip_bfloat16*)ws;
    __hip_bfloat16* Yp = (__hip_bfloat16*)(ws + patSz);
    float* x2 = (float*)(ws + 2 * patSz);
    float* y2 = x2 + BATCH * NPAD;
    float* row_min = y2 + BATCH * NPAD;
    float2* yr = (float2*)(row_min + BATCH * NPAD);

    dim3 eg(NPAD / 4, BATCH);
    extract_patches<<<eg, 256, 0, stream>>>(x, Xp, x2, out);   // zeroes out
    extract_patches<<<eg, 256, 0, stream>>>(y, Yp, y2, nullptr);

    panel_pass<1><<<NT * BATCH, 1024, 0, stream>>>(Xp, Yp, x2, y2, yr,
                                                   row_min, out);
    prep_rms<<<(BATCH * NPAD) / 256, 256, 0, stream>>>(row_min, y2, yr);
    panel_pass<2><<<NT * BATCH, 1024, 0, stream>>>(Xp, Yp, x2, y2, yr,
                                                   row_min, out);
}

// Round 12
// 258.146 us; speedup vs baseline: 1.0001x; 1.0001x over previous
//
#include <hip/hip_runtime.h>
#include <hip/hip_bf16.h>
#include <stdint.h>

#define IMG_H 96
#define IMG_W 96
#define IMG_C 3
#define HO    90                 // 96-7+1
#define NPAT  8100               // 90*90
#define NPAD  8192
#define DDIM  147                // 3*7*7
#define KPAD  160                // padded K (5 chunks of 32)
#define NCHK  5
#define BATCH 4
#define TILE  128
#define NT    (NPAD / TILE)      // 64 stream tiles
#define ALPHA 0.05f

typedef __attribute__((ext_vector_type(8))) short short8;
typedef __attribute__((ext_vector_type(4))) float f32x4;

__device__ __forceinline__ void async16(const void* g, void* l) {
    __builtin_amdgcn_global_load_lds(
        (const __attribute__((address_space(1))) unsigned int*)g,
        (__attribute__((address_space(3))) unsigned int*)l,
        16, 0, 0);
}

// ---------- patch extraction + squared norms (+ out zero) ----------
__global__ __launch_bounds__(256) void extract_patches(
    const float* __restrict__ img,          // [B][3][96][96]
    __hip_bfloat16* __restrict__ pat,       // [B][NPAD][KPAD]
    float* __restrict__ nrm,                // [B][NPAD]
    float* __restrict__ outzero)            // may be null
{
    int wid  = threadIdx.x >> 6;
    int lane = threadIdx.x & 63;
    int pidx = blockIdx.x * 4 + wid;        // 0..8191
    int b    = blockIdx.y;
    if (pidx >= NPAD) return;
    if (outzero && blockIdx.x == 0 && blockIdx.y == 0 && threadIdx.x == 0)
        outzero[0] = 0.f;
    const float* im = img + (size_t)b * (IMG_C * IMG_H * IMG_W);
    __hip_bfloat16* pp = pat + ((size_t)b * NPAD + pidx) * KPAD;
    int r = pidx / HO, c = pidx - r * HO;
    bool valid = pidx < NPAT;
    float ss = 0.f;
    for (int d = lane; d < KPAD; d += 64) {
        float v = 0.f;
        if (valid && d < DDIM) {
            int ch  = d / 49;
            int rem = d - ch * 49;
            int pr  = rem / 7, pc = rem - pr * 7;
            v = im[ch * (IMG_H * IMG_W) + (r + pr) * IMG_W + (c + pc)];
        }
        pp[d] = __float2bfloat16(v);
        ss += v * v;
    }
    for (int s = 32; s; s >>= 1) ss += __shfl_down(ss, s);
    if (lane == 0) nrm[(size_t)b * NPAD + pidx] = ss;
}

// ---------- prep: rms = invD/(row_min+a) (inf pads) fused with y2 -> float2 ----------
__global__ __launch_bounds__(256) void prep_rms(
    const float* __restrict__ row_min, const float* __restrict__ y2,
    float2* __restrict__ yr)
{
    int i = blockIdx.x * 256 + threadIdx.x;
    if (i < BATCH * NPAD) {
        int j = i & (NPAD - 1);
        float rm = row_min[i];
        float rr = (j < NPAT) ? (1.0f / (float)DDIM) / (rm + ALPHA)
                              : __builtin_inff();
        yr[i] = make_float2(y2[i], rr);
    }
}

// -------------------- panel-persistent fused GEMM passes --------------------
// 1024 threads = 16 waves = 4 waves/SIMD. __launch_bounds__(1024, 4) declares
// 4 waves/EU -> VGPR cap 128 (not 64): p_reg[5][4] (80 VGPR) STAYS IN
// REGISTERS. R11's default cap (64) spilled it to scratch: WRITE_SIZE 8.3 MB,
// 148 us. Structure otherwise identical to the verified R11.
// Wave layout: wp=wid>>3 (2 x 64 panel rows), ws=wid&7 (8 x 16 stream cols).
// PASS 1: row-min in regs -> plain store per row (no atomics).
// PASS 2: col-min in regs -> one atomicAdd partial per block.
template <int PASS>
__global__ __launch_bounds__(1024, 4) void panel_pass(
    const __hip_bfloat16* __restrict__ Xp,   // [B][NPAD][KPAD]
    const __hip_bfloat16* __restrict__ Yp,   // [B][NPAD][KPAD]
    const float* __restrict__ x2,
    const float* __restrict__ y2,
    const float2* __restrict__ yr,           // PASS2: (y2, rms) pairs
    float* __restrict__ row_min,
    float* __restrict__ out)                 // PASS2 only
{
    __shared__ __align__(16) __hip_bfloat16 S[2][NCHK * TILE * 32]; // 2 x 40 KB
    __shared__ __align__(16) float  sm_a[2][TILE];    // PASS1: stream x2
    __shared__ __align__(16) float2 sm_yr[2][TILE];   // PASS2: stream (y2,rms)
    __shared__ __align__(16) float  pnl[TILE];        // panel: y2 (P1) / x2 (P2)
    __shared__ float red[8][TILE];                    // cross-wave reduce

    int blk = blockIdx.x;
    int bz  = blk & 3;               // image (XCD-locality under %8 rr)
    int tP  = blk >> 2;              // panel index 0..63
    int tid = threadIdx.x;
    int wid = tid >> 6, lane = tid & 63;
    int wp  = wid >> 3;              // panel half (2 x 64 rows)
    int ws  = wid & 7;               // stream group (8 x 16 cols)

    const __hip_bfloat16* Pbase =
        (PASS == 1 ? Yp : Xp) + ((size_t)bz * NPAD + tP * TILE) * KPAD;
    const __hip_bfloat16* Sbase =
        (PASS == 1 ? Xp : Yp) + (size_t)bz * NPAD * KPAD;
    const float* pnl_src = (PASS == 1 ? y2 : x2) + (size_t)bz * NPAD + tP * TILE;
    const float*  sma_src = x2 + (size_t)bz * NPAD;           // PASS1
    const float2* syr_src = yr + (size_t)bz * NPAD;           // PASS2

    // stage one 128x160 tile: waves 0-7, 5 async16/thread (inverse-swz source)
    auto stageS = [&](int buf, const __hip_bfloat16* gsrc) {
        if (wid < 8) {
            int row  = wid * 16 + (lane >> 2);
            int slog = (lane & 3) ^ ((row >> 1) & 3);
            const __hip_bfloat16* src = gsrc + (size_t)row * KPAD + slog * 8;
            __hip_bfloat16* dbase = &S[buf][wid * 512];
            for (int c = 0; c < NCHK; ++c)
                async16(src + c * 32, dbase + c * 4096);
        }
    };
    auto stage_small = [&](int buf, int t) {
        if (PASS == 1) {
            if (wid == 8 && lane < 32)       // 32 lanes x 4 floats = 128
                async16(sma_src + (size_t)t * TILE + lane * 4, &sm_a[buf][0]);
        } else {
            if (wid == 8)                    // 64 lanes x 2 float2 = 128
                async16(syr_src + (size_t)t * TILE + lane * 2, &sm_yr[buf][0]);
        }
    };

    // prologue: panel -> S1; tile0 -> S0; smalls; panel scalars
    stageS(1, Pbase);
    stageS(0, Sbase);
    stage_small(0, 0);
    if (wid == 9 && lane < 32) async16(pnl_src + lane * 4, &pnl[0]);
    __syncthreads();                 // drain: everything landed

    int fr    = lane & 15;
    int sread = ((lane >> 4) ^ ((lane >> 1) & 3)) * 8;  // swizzled 16B slot
    int prow  = wp * 64 + fr;
    int srow  = ws * 16 + fr;

    // panel fragments -> registers (20 ds_read_b128, once)
    short8 p_reg[NCHK][4];
#pragma unroll
    for (int c = 0; c < NCHK; ++c)
#pragma unroll
        for (int m = 0; m < 4; ++m)
            p_reg[c][m] =
                *(const short8*)&S[1][c * 4096 + (prow + m * 16) * 32 + sread];

    float xv[4];   // PASS2: own panel cols' x2
    if (PASS == 2)
#pragma unroll
        for (int nb = 0; nb < 4; ++nb) xv[nb] = pnl[wp * 64 + nb * 16 + fr];

    __syncthreads();   // lgkmcnt(0) drained: p_reg in regs before S1 reuse

    float runmin[PASS == 1 ? 16 : 4];
#pragma unroll
    for (int i = 0; i < (PASS == 1 ? 16 : 4); ++i)
        runmin[i] = __builtin_inff();

#pragma unroll 1
    for (int t = 0; t < NT; ++t) {
        int cur = t & 1;
        if (t + 1 < NT) {            // prefetch next tile (hidden under compute)
            stageS(cur ^ 1, Sbase + (size_t)(t + 1) * TILE * KPAD);
            stage_small(cur ^ 1, t + 1);
        }

        const __hip_bfloat16* Sc = &S[cur][0];

        f32x4 acc[4] = {};
#pragma unroll
        for (int c = 0; c < NCHK; ++c) {
            short8 s0 = *(const short8*)&Sc[c * 4096 + srow * 32 + sread];
            if (PASS == 1) {
#pragma unroll
                for (int m = 0; m < 4; ++m)
                    acc[m] = __builtin_amdgcn_mfma_f32_16x16x32_bf16(
                        p_reg[c][m], s0, acc[m], 0, 0, 0);
            } else {
#pragma unroll
                for (int nb = 0; nb < 4; ++nb)
                    acc[nb] = __builtin_amdgcn_mfma_f32_16x16x32_bf16(
                        s0, p_reg[c][nb], acc[nb], 0, 0, 0);
            }
        }

        if (PASS == 1) {
            int ic = ws * 16 + fr;
            float xx = sm_a[cur][ic];
            float xvn = (t * TILE + ic < NPAT) ? xx : __builtin_inff();
#pragma unroll
            for (int m = 0; m < 4; ++m)
#pragma unroll
                for (int reg = 0; reg < 4; ++reg)
                    runmin[m * 4 + reg] = fminf(runmin[m * 4 + reg],
                        fmaf(-2.0f, acc[m][reg], xvn));
        } else {
#pragma unroll
            for (int reg = 0; reg < 4; ++reg) {
                int jl = ws * 16 + (lane >> 4) * 4 + reg;
                float2 p = sm_yr[cur][jl];   // (y2, rms); rms=inf on pad rows
#pragma unroll
                for (int nb = 0; nb < 4; ++nb)
                    runmin[nb] = fminf(runmin[nb],
                        fmaf(-2.0f, acc[nb][reg], p.x + xv[nb]) * p.y);
            }
        }
        __syncthreads();             // drains prefetch + buffer handshake
    }

    if (PASS == 1) {
        // reduce over 16 stream cols (lane fr dim) -> cross-ws -> plain store
#pragma unroll
        for (int m = 0; m < 4; ++m)
#pragma unroll
            for (int reg = 0; reg < 4; ++reg) {
                float v = runmin[m * 4 + reg];
                for (int s = 1; s < 16; s <<= 1)
                    v = fminf(v, __shfl_xor(v, s));
                if ((lane & 15) == 0)
                    red[ws][wp * 64 + m * 16 + (lane >> 4) * 4 + reg] = v;
            }
        __syncthreads();
        if (tid < TILE) {
            float mv = red[0][tid];
#pragma unroll
            for (int w = 1; w < 8; ++w) mv = fminf(mv, red[w][tid]);
            row_min[(size_t)bz * NPAD + tP * TILE + tid] =
                fmaxf(pnl[tid] + mv, 0.f) * (1.0f / (float)DDIM);
        }
    } else {
        // reduce over stream rows -> cross-ws -> clamp/mask -> 1 atomic
#pragma unroll
        for (int nb = 0; nb < 4; ++nb) {
            float v = runmin[nb];
            v = fminf(v, __shfl_xor(v, 16));
            v = fminf(v, __shfl_xor(v, 32));
            if (lane < 16) red[ws][wp * 64 + nb * 16 + lane] = v;
        }
        __syncthreads();
        if (tid < TILE) {
            int gc = tP * TILE + tid;
            float cv = red[0][tid];
#pragma unroll
            for (int w = 1; w < 8; ++w) cv = fminf(cv, red[w][tid]);
            cv = fmaxf(cv, 0.f);                   // deferred clamp (monotone)
            red[0][tid] = (gc < NPAT) ? cv : 0.f;  // mask pad cols
        }
        __syncthreads();
        if (tid < 64) {
            float s = red[0][tid] + red[0][tid + 64];
            for (int o = 32; o; o >>= 1) s += __shfl_down(s, o);
            if (tid == 0)
                atomicAdd(out, s * (1.0f / (float)(BATCH * NPAT)));
        }
    }
}

extern "C" void kernel_launch(void* const* d_in, const int* in_sizes, int n_in,
                              void* d_out, int out_size, void* d_ws, size_t ws_size,
                              hipStream_t stream) {
    const float* x = (const float*)d_in[0];
    const float* y = (const float*)d_in[1];
    float* out = (float*)d_out;

    char* ws = (char*)d_ws;
    size_t patSz = (size_t)BATCH * NPAD * KPAD * sizeof(__hip_bfloat16); // 10.5 MB
    __hip_bfloat16* Xp = (__hip_bfloat16*)ws;
    __hip_bfloat16* Yp = (__hip_bfloat16*)(ws + patSz);
    float* x2 = (float*)(ws + 2 * patSz);
    float* y2 = x2 + BATCH * NPAD;
    float* row_min = y2 + BATCH * NPAD;
    float2* yr = (float2*)(row_min + BATCH * NPAD);

    dim3 eg(NPAD / 4, BATCH);
    extract_patches<<<eg, 256, 0, stream>>>(x, Xp, x2, out);   // zeroes out
    extract_patches<<<eg, 256, 0, stream>>>(y, Yp, y2, nullptr);

    panel_pass<1><<<NT * BATCH, 1024, 0, stream>>>(Xp, Yp, x2, y2, yr,
                                                   row_min, out);
    prep_rms<<<(BATCH * NPAD) / 256, 256, 0, stream>>>(row_min, y2, yr);
    panel_pass<2><<<NT * BATCH, 1024, 0, stream>>>(Xp, Yp, x2, y2, yr,
                                                   row_min, out);
}

// Round 13
// 229.095 us; speedup vs baseline: 1.1269x; 1.1268x over previous
//
#include <hip/hip_runtime.h>
#include <hip/hip_bf16.h>
#include <stdint.h>

#define IMG_H 96
#define IMG_W 96
#define IMG_C 3
#define HO    90                 // 96-7+1
#define NPAT  8100               // 90*90
#define NPAD  8192
#define DDIM  147                // 3*7*7
#define KPAD  160                // padded K (5 chunks of 32)
#define NCHK  5
#define BATCH 4
#define PNL   64                 // panel rows per block
#define SRT   128                // stream rows per tile
#define NT    (NPAD / SRT)       // 64 stream tiles
#define ALPHA 0.05f

typedef __attribute__((ext_vector_type(8))) short short8;
typedef __attribute__((ext_vector_type(4))) float f32x4;

__device__ __forceinline__ void async16(const void* g, void* l) {
    __builtin_amdgcn_global_load_lds(
        (const __attribute__((address_space(1))) unsigned int*)g,
        (__attribute__((address_space(3))) unsigned int*)l,
        16, 0, 0);
}

// ---------- patch extraction + squared norms (+ out zero) ----------
__global__ __launch_bounds__(256) void extract_patches(
    const float* __restrict__ img,          // [B][3][96][96]
    __hip_bfloat16* __restrict__ pat,       // [B][NPAD][KPAD]
    float* __restrict__ nrm,                // [B][NPAD]
    float* __restrict__ outzero)            // may be null
{
    int wid  = threadIdx.x >> 6;
    int lane = threadIdx.x & 63;
    int pidx = blockIdx.x * 4 + wid;        // 0..8191
    int b    = blockIdx.y;
    if (pidx >= NPAD) return;
    if (outzero && blockIdx.x == 0 && blockIdx.y == 0 && threadIdx.x == 0)
        outzero[0] = 0.f;
    const float* im = img + (size_t)b * (IMG_C * IMG_H * IMG_W);
    __hip_bfloat16* pp = pat + ((size_t)b * NPAD + pidx) * KPAD;
    int r = pidx / HO, c = pidx - r * HO;
    bool valid = pidx < NPAT;
    float ss = 0.f;
    for (int d = lane; d < KPAD; d += 64) {
        float v = 0.f;
        if (valid && d < DDIM) {
            int ch  = d / 49;
            int rem = d - ch * 49;
            int pr  = rem / 7, pc = rem - pr * 7;
            v = im[ch * (IMG_H * IMG_W) + (r + pr) * IMG_W + (c + pc)];
        }
        pp[d] = __float2bfloat16(v);
        ss += v * v;
    }
    for (int s = 32; s; s >>= 1) ss += __shfl_down(ss, s);
    if (lane == 0) nrm[(size_t)b * NPAD + pidx] = ss;
}

// ---------- prep: (y2, rms) float2; rms = invD/(row_min+a), inf on pads ----------
__global__ __launch_bounds__(256) void prep_rms(
    const float* __restrict__ row_min, const float* __restrict__ y2,
    float2* __restrict__ yr)
{
    int i = blockIdx.x * 256 + threadIdx.x;
    if (i < BATCH * NPAD) {
        int j = i & (NPAD - 1);
        float rm = row_min[i];
        float rr = (j < NPAT) ? (1.0f / (float)DDIM) / (rm + ALPHA)
                              : __builtin_inff();
        yr[i] = make_float2(y2[i], rr);
    }
}

// -------------------- panel-persistent fused GEMM passes --------------------
// 512 blocks (64-row panels x 4 images) x 512 threads -> 2 blocks/CU
// (16 waves/CU = 4 waves/SIMD) WITHOUT the 1024-thread VGPR-64 cap.
// Every wave holds the FULL 64-row panel in p_reg[5][4] (80 VGPR, ratio-4:
// 20 MFMA per 5 ds_read per tile) and owns stream rows [wid*16, wid*16+16).
// LDS = EXACTLY 2x40KB stream dbuf (81920B): epilogue red[] aliases into S;
// all per-tile scalars are direct per-lane global loads (L2-hit, hidden).
// PASS 1: row-min in regs -> plain store per panel row (no atomics).
// PASS 2: col-min in regs -> one atomicAdd partial per block.
template <int PASS>
__global__ __launch_bounds__(512, 2) void panel_pass(
    const __hip_bfloat16* __restrict__ Xp,   // [B][NPAD][KPAD]
    const __hip_bfloat16* __restrict__ Yp,   // [B][NPAD][KPAD]
    const float* __restrict__ x2,
    const float* __restrict__ y2,
    const float2* __restrict__ yr,           // PASS2: (y2, rms) pairs
    float* __restrict__ row_min,
    float* __restrict__ out)                 // PASS2 only
{
    __shared__ __align__(16) __hip_bfloat16 S[2][NCHK * SRT * 32]; // 81920 B

    int blk = blockIdx.x;
    int bz  = blk & 3;               // image (XCD-locality under %8 rr)
    int tP  = blk >> 2;              // panel index 0..127
    int tid = threadIdx.x;
    int wid = tid >> 6, lane = tid & 63;
    int fr  = lane & 15;

    const __hip_bfloat16* Pbase =
        (PASS == 1 ? Yp : Xp) + ((size_t)bz * NPAD + tP * PNL) * KPAD;
    const __hip_bfloat16* Sbase =
        (PASS == 1 ? Xp : Yp) + (size_t)bz * NPAD * KPAD;
    const float*  sx2 = x2 + (size_t)bz * NPAD;   // PASS1 stream scalars
    const float2* syr = yr + (size_t)bz * NPAD;   // PASS2 stream scalars

    // stage one 128x160 stream tile: all 8 waves, 5 async16/thread
    auto stageS = [&](int buf, const __hip_bfloat16* gsrc) {
        int row  = wid * 16 + (lane >> 2);
        int slog = (lane & 3) ^ ((row >> 1) & 3);        // inverse swz on src
        const __hip_bfloat16* src = gsrc + (size_t)row * KPAD + slog * 8;
        __hip_bfloat16* dst = &S[buf][wid * 512];
        for (int c = 0; c < NCHK; ++c)
            async16(src + c * 32, dst + c * 4096);
    };

    // prologue: panel (64 rows, waves 0-3) -> S[1]; tile0 -> S[0]
    if (wid < 4) {
        int row  = wid * 16 + (lane >> 2);
        int slog = (lane & 3) ^ ((row >> 1) & 3);
        const __hip_bfloat16* src = Pbase + (size_t)row * KPAD + slog * 8;
        __hip_bfloat16* dst = &S[1][wid * 512];
        for (int c = 0; c < NCHK; ++c)
            async16(src + c * 32, dst + c * 4096);
    }
    stageS(0, Sbase);
    __syncthreads();                 // drain: panel + tile0 landed

    int sread = ((lane >> 4) ^ ((lane >> 1) & 3)) * 8;   // swizzled 16B slot

    // full panel -> registers (20 ds_read_b128, every wave)
    short8 p_reg[NCHK][4];
#pragma unroll
    for (int c = 0; c < NCHK; ++c)
#pragma unroll
        for (int m = 0; m < 4; ++m)
            p_reg[c][m] =
                *(const short8*)&S[1][c * 4096 + (m * 16 + fr) * 32 + sread];

    float xv[4];   // PASS2: panel cols' x2 (direct global, once)
    if (PASS == 2)
#pragma unroll
        for (int nb = 0; nb < 4; ++nb)
            xv[nb] = x2[(size_t)bz * NPAD + tP * PNL + nb * 16 + fr];

    __syncthreads();                 // p_reg in regs before S[1] is reused

    float runmin[PASS == 1 ? 16 : 4];
#pragma unroll
    for (int i = 0; i < (PASS == 1 ? 16 : 4); ++i)
        runmin[i] = __builtin_inff();

    int srow = wid * 16 + fr;        // wave's stream slice row (B-col / A-row)

#pragma unroll 1
    for (int t = 0; t < NT; ++t) {
        int cur = t & 1;
        if (t + 1 < NT)              // prefetch next tile (hidden under compute)
            stageS(cur ^ 1, Sbase + (size_t)(t + 1) * SRT * KPAD);

        // per-tile stream scalars: direct global (L2), consumed after MFMA
        float xg = 0.f;
        float2 pq[4];
        if (PASS == 1) {
            int ic = t * SRT + srow;
            xg = (ic < NPAT) ? sx2[ic] : __builtin_inff();
        } else {
#pragma unroll
            for (int reg = 0; reg < 4; ++reg)
                pq[reg] = syr[t * SRT + wid * 16 + (lane >> 4) * 4 + reg];
        }

        const __hip_bfloat16* Sc = &S[cur][0];
        f32x4 acc[4] = {};
#pragma unroll
        for (int c = 0; c < NCHK; ++c) {
            short8 s0 = *(const short8*)&Sc[c * 4096 + srow * 32 + sread];
            if (PASS == 1) {
#pragma unroll
                for (int m = 0; m < 4; ++m)
                    acc[m] = __builtin_amdgcn_mfma_f32_16x16x32_bf16(
                        p_reg[c][m], s0, acc[m], 0, 0, 0);
            } else {
#pragma unroll
                for (int nb = 0; nb < 4; ++nb)
                    acc[nb] = __builtin_amdgcn_mfma_f32_16x16x32_bf16(
                        s0, p_reg[c][nb], acc[nb], 0, 0, 0);
            }
        }

        if (PASS == 1) {
            // acc[m][reg]: row = panel m*16+(lane>>4)*4+reg, col = stream srow
#pragma unroll
            for (int m = 0; m < 4; ++m)
#pragma unroll
                for (int reg = 0; reg < 4; ++reg)
                    runmin[m * 4 + reg] = fminf(runmin[m * 4 + reg],
                        fmaf(-2.0f, acc[m][reg], xg));
        } else {
            // acc[nb][reg]: row = stream wid*16+(lane>>4)*4+reg, col = panel nb*16+fr
#pragma unroll
            for (int reg = 0; reg < 4; ++reg) {
                float yv = pq[reg].x, rr = pq[reg].y;  // rr=inf on pad rows
#pragma unroll
                for (int nb = 0; nb < 4; ++nb)
                    runmin[nb] = fminf(runmin[nb],
                        fmaf(-2.0f, acc[nb][reg], yv + xv[nb]) * rr);
            }
        }
        __syncthreads();             // drains prefetch + buffer handshake
    }

    // epilogue scratch aliases into S (dead after loop's final barrier)
    float* red = (float*)&S[0][0];   // [8][PNL]

    if (PASS == 1) {
        // reduce over stream cols (fr lanes) -> cross-wave -> plain store
#pragma unroll
        for (int m = 0; m < 4; ++m)
#pragma unroll
            for (int reg = 0; reg < 4; ++reg) {
                float v = runmin[m * 4 + reg];
                for (int s = 1; s < 16; s <<= 1)
                    v = fminf(v, __shfl_xor(v, s));
                if (fr == 0)
                    red[wid * PNL + m * 16 + (lane >> 4) * 4 + reg] = v;
            }
        __syncthreads();
        if (tid < PNL) {
            float mv = red[tid];
#pragma unroll
            for (int w = 1; w < 8; ++w) mv = fminf(mv, red[w * PNL + tid]);
            float y2g = y2[(size_t)bz * NPAD + tP * PNL + tid];
            row_min[(size_t)bz * NPAD + tP * PNL + tid] =
                fmaxf(y2g + mv, 0.f) * (1.0f / (float)DDIM);
        }
    } else {
        // reduce over stream rows -> cross-wave -> clamp/mask -> 1 atomic
#pragma unroll
        for (int nb = 0; nb < 4; ++nb) {
            float v = runmin[nb];
            v = fminf(v, __shfl_xor(v, 16));
            v = fminf(v, __shfl_xor(v, 32));
            if (lane < 16) red[wid * PNL + nb * 16 + lane] = v;
        }
        __syncthreads();
        if (tid < PNL) {
            int gc = tP * PNL + tid;
            float cv = red[tid];
#pragma unroll
            for (int w = 1; w < 8; ++w) cv = fminf(cv, red[w * PNL + tid]);
            cv = fmaxf(cv, 0.f);                   // deferred clamp (monotone)
            float s = (gc < NPAT) ? cv : 0.f;      // mask pad cols
            for (int o = 32; o; o >>= 1) s += __shfl_down(s, o);
            if (tid == 0)
                atomicAdd(out, s * (1.0f / (float)(BATCH * NPAT)));
        }
    }
}

extern "C" void kernel_launch(void* const* d_in, const int* in_sizes, int n_in,
                              void* d_out, int out_size, void* d_ws, size_t ws_size,
                              hipStream_t stream) {
    const float* x = (const float*)d_in[0];
    const float* y = (const float*)d_in[1];
    float* out = (float*)d_out;

    char* ws = (char*)d_ws;
    size_t patSz = (size_t)BATCH * NPAD * KPAD * sizeof(__hip_bfloat16); // 10.5 MB
    __hip_bfloat16* Xp = (__hip_bfloat16*)ws;
    __hip_bfloat16* Yp = (__hip_bfloat16*)(ws + patSz);
    float* x2 = (float*)(ws + 2 * patSz);
    float* y2 = x2 + BATCH * NPAD;
    float* row_min = y2 + BATCH * NPAD;
    float2* yr = (float2*)(row_min + BATCH * NPAD);

    dim3 eg(NPAD / 4, BATCH);
    extract_patches<<<eg, 256, 0, stream>>>(x, Xp, x2, out);   // zeroes out
    extract_patches<<<eg, 256, 0, stream>>>(y, Yp, y2, nullptr);

    int nblk = (NPAD / PNL) * BATCH;    // 512 blocks -> 2 per CU
    panel_pass<1><<<nblk, 512, 0, stream>>>(Xp, Yp, x2, y2, yr, row_min, out);
    prep_rms<<<(BATCH * NPAD) / 256, 256, 0, stream>>>(row_min, y2, yr);
    panel_pass<2><<<nblk, 512, 0, stream>>>(Xp, Yp, x2, y2, yr, row_min, out);
}

// Round 14
// 225.131 us; speedup vs baseline: 1.1467x; 1.0176x over previous
//
#include <hip/hip_runtime.h>
#include <hip/hip_bf16.h>
#include <stdint.h>

#define IMG_H 96
#define IMG_W 96
#define IMG_C 3
#define HO    90                 // 96-7+1
#define NPAT  8100               // 90*90
#define NPAD  8192
#define DDIM  147                // 3*7*7
#define KPAD  160                // padded K (5 chunks of 32)
#define NCHK  5
#define BATCH 4
#define PNL   64                 // panel rows per block
#define SRT   128                // stream rows per tile
#define NT    (NPAD / SRT)       // 64 stream tiles (even -> unroll-by-2 OK)
#define ALPHA 0.05f

typedef __attribute__((ext_vector_type(8))) short short8;
typedef __attribute__((ext_vector_type(4))) float f32x4;

__device__ __forceinline__ void async16(const void* g, void* l) {
    __builtin_amdgcn_global_load_lds(
        (const __attribute__((address_space(1))) unsigned int*)g,
        (__attribute__((address_space(3))) unsigned int*)l,
        16, 0, 0);
}

// ---------- patch extraction + squared norms (+ out zero) ----------
__global__ __launch_bounds__(256) void extract_patches(
    const float* __restrict__ img,          // [B][3][96][96]
    __hip_bfloat16* __restrict__ pat,       // [B][NPAD][KPAD]
    float* __restrict__ nrm,                // [B][NPAD]
    float* __restrict__ outzero)            // may be null
{
    int wid  = threadIdx.x >> 6;
    int lane = threadIdx.x & 63;
    int pidx = blockIdx.x * 4 + wid;        // 0..8191
    int b    = blockIdx.y;
    if (pidx >= NPAD) return;
    if (outzero && blockIdx.x == 0 && blockIdx.y == 0 && threadIdx.x == 0)
        outzero[0] = 0.f;
    const float* im = img + (size_t)b * (IMG_C * IMG_H * IMG_W);
    __hip_bfloat16* pp = pat + ((size_t)b * NPAD + pidx) * KPAD;
    int r = pidx / HO, c = pidx - r * HO;
    bool valid = pidx < NPAT;
    float ss = 0.f;
    for (int d = lane; d < KPAD; d += 64) {
        float v = 0.f;
        if (valid && d < DDIM) {
            int ch  = d / 49;
            int rem = d - ch * 49;
            int pr  = rem / 7, pc = rem - pr * 7;
            v = im[ch * (IMG_H * IMG_W) + (r + pr) * IMG_W + (c + pc)];
        }
        pp[d] = __float2bfloat16(v);
        ss += v * v;
    }
    for (int s = 32; s; s >>= 1) ss += __shfl_down(ss, s);
    if (lane == 0) nrm[(size_t)b * NPAD + pidx] = ss;
}

// ---------- prep: (y2, rms) float2; rms = invD/(row_min+a), inf on pads ----------
__global__ __launch_bounds__(256) void prep_rms(
    const float* __restrict__ row_min, const float* __restrict__ y2,
    float2* __restrict__ yr)
{
    int i = blockIdx.x * 256 + threadIdx.x;
    if (i < BATCH * NPAD) {
        int j = i & (NPAD - 1);
        float rm = row_min[i];
        float rr = (j < NPAT) ? (1.0f / (float)DDIM) / (rm + ALPHA)
                              : __builtin_inff();
        yr[i] = make_float2(y2[i], rr);
    }
}

// -------------------- panel-persistent, LDS-free hot loop --------------------
// 512 blocks x 512 threads -> 2 blocks/CU (grid-limited) = 4 waves/SIMD.
// Panel (64 rows) in p_reg[5][4] (staged once via 20 KB LDS, then LDS dead).
// Stream fragments loaded DIRECTLY from global (XCD-L2-resident: image per
// XCD, 2.6 MB < 4 MB) into register double-buffer (A/B, unroll-by-2 so all
// indices are compile-time). NO barriers / LDS / vmcnt in the loop: next
// tile's 5 loads hide under current tile's 20 MFMAs; blocks drift freely.
// PASS 1: row-min in regs -> plain store per panel row (no atomics).
// PASS 2: col-min in regs -> one atomicAdd partial per block.
template <int PASS>
__global__ __launch_bounds__(512, 2) void panel_pass(
    const __hip_bfloat16* __restrict__ Xp,   // [B][NPAD][KPAD]
    const __hip_bfloat16* __restrict__ Yp,   // [B][NPAD][KPAD]
    const float* __restrict__ x2,
    const float* __restrict__ y2,
    const float2* __restrict__ yr,           // PASS2: (y2, rms) pairs
    float* __restrict__ row_min,
    float* __restrict__ out)                 // PASS2 only
{
    __shared__ __align__(16) __hip_bfloat16 S[NCHK * PNL * 32];  // 20480 B

    int blk = blockIdx.x;
    int bz  = blk & 3;               // image: fixed per XCD under %8 rr
    int tP  = blk >> 2;              // panel index 0..127
    int tid = threadIdx.x;
    int wid = tid >> 6, lane = tid & 63;
    int fr  = lane & 15;
    int koq = lane >> 4;             // k-quad 0..3

    const __hip_bfloat16* Pbase =
        (PASS == 1 ? Yp : Xp) + ((size_t)bz * NPAD + tP * PNL) * KPAD;
    const __hip_bfloat16* Sbase =
        (PASS == 1 ? Xp : Yp) + (size_t)bz * NPAD * KPAD;
    const float*  sx2 = x2 + (size_t)bz * NPAD;   // PASS1 stream scalars
    const float2* syr = yr + (size_t)bz * NPAD;   // PASS2 stream scalars

    // ---- one-shot panel stage (waves 0-3) + p_reg load; LDS dead after ----
    if (wid < 4) {
        int row  = wid * 16 + (lane >> 2);
        int slog = (lane & 3) ^ ((row >> 1) & 3);          // inverse swz on src
        const __hip_bfloat16* src = Pbase + (size_t)row * KPAD + slog * 8;
        __hip_bfloat16* dst = &S[wid * 512];
        for (int c = 0; c < NCHK; ++c)
            async16(src + c * 32, dst + c * 4096);
    }
    __syncthreads();

    int sread = (koq ^ ((lane >> 1) & 3)) * 8;             // swizzled 16B slot
    short8 p_reg[NCHK][4];
#pragma unroll
    for (int c = 0; c < NCHK; ++c)
#pragma unroll
        for (int m = 0; m < 4; ++m)
            p_reg[c][m] =
                *(const short8*)&S[c * 4096 + (m * 16 + fr) * 32 + sread];

    float xv[4];   // PASS2: panel cols' x2 (direct global, once)
    if (PASS == 2)
#pragma unroll
        for (int nb = 0; nb < 4; ++nb)
            xv[nb] = x2[(size_t)bz * NPAD + tP * PNL + nb * 16 + fr];

    __syncthreads();   // all waves past p_reg reads; S reusable at epilogue

    float runmin[PASS == 1 ? 16 : 4];
#pragma unroll
    for (int i = 0; i < (PASS == 1 ? 16 : 4); ++i)
        runmin[i] = __builtin_inff();

    int srow = wid * 16 + fr;        // wave's stream slice row within tile
    // per-lane stream fragment pointer: row (t*SRT + srow), 16B at koq*8
    const __hip_bfloat16* sp =
        Sbase + (size_t)srow * KPAD + koq * 8;

    // load tile t's 5 fragments into regs
    auto loadf = [&](short8 (&f)[NCHK], int t) {
        const __hip_bfloat16* p = sp + (size_t)t * SRT * KPAD;
#pragma unroll
        for (int c = 0; c < NCHK; ++c)
            f[c] = *(const short8*)(p + c * 32);
    };

    // compute tile t from fragments f, prefetch tile t+1 into g
    auto body = [&](short8 (&f)[NCHK], short8 (&g)[NCHK], int t) {
        if (t + 1 < NT) loadf(g, t + 1);           // in flight under MFMAs

        float xg = 0.f;
        float2 pq[4];
        if (PASS == 1) {
            int ic = t * SRT + srow;
            xg = (ic < NPAT) ? sx2[ic] : __builtin_inff();
        } else {
#pragma unroll
            for (int reg = 0; reg < 4; ++reg)
                pq[reg] = syr[t * SRT + wid * 16 + koq * 4 + reg];
        }

        f32x4 acc[4] = {};
#pragma unroll
        for (int c = 0; c < NCHK; ++c) {
            if (PASS == 1) {
#pragma unroll
                for (int m = 0; m < 4; ++m)
                    acc[m] = __builtin_amdgcn_mfma_f32_16x16x32_bf16(
                        p_reg[c][m], f[c], acc[m], 0, 0, 0);
            } else {
#pragma unroll
                for (int nb = 0; nb < 4; ++nb)
                    acc[nb] = __builtin_amdgcn_mfma_f32_16x16x32_bf16(
                        f[c], p_reg[c][nb], acc[nb], 0, 0, 0);
            }
        }

        if (PASS == 1) {
            // acc[m][reg]: row = panel m*16+koq*4+reg, col = stream srow
#pragma unroll
            for (int m = 0; m < 4; ++m)
#pragma unroll
                for (int reg = 0; reg < 4; ++reg)
                    runmin[m * 4 + reg] = fminf(runmin[m * 4 + reg],
                        fmaf(-2.0f, acc[m][reg], xg));
        } else {
            // acc[nb][reg]: row = stream wid*16+koq*4+reg, col = panel nb*16+fr
#pragma unroll
            for (int reg = 0; reg < 4; ++reg) {
                float yv = pq[reg].x, rr = pq[reg].y;   // rr=inf on pad rows
#pragma unroll
                for (int nb = 0; nb < 4; ++nb)
                    runmin[nb] = fminf(runmin[nb],
                        fmaf(-2.0f, acc[nb][reg], yv + xv[nb]) * rr);
            }
        }
    };

    short8 fA[NCHK], fB[NCHK];
    loadf(fA, 0);
#pragma unroll 1
    for (int t = 0; t < NT; t += 2) {   // NT even: A/B ping-pong, static idx
        body(fA, fB, t);
        body(fB, fA, t + 1);
    }

    // epilogue scratch aliases into S (dead since pre-loop barrier)
    float* red = (float*)&S[0];      // [8][PNL]

    if (PASS == 1) {
        // reduce over stream cols (fr lanes) -> cross-wave -> plain store
#pragma unroll
        for (int m = 0; m < 4; ++m)
#pragma unroll
            for (int reg = 0; reg < 4; ++reg) {
                float v = runmin[m * 4 + reg];
                for (int s = 1; s < 16; s <<= 1)
                    v = fminf(v, __shfl_xor(v, s));
                if (fr == 0)
                    red[wid * PNL + m * 16 + koq * 4 + reg] = v;
            }
        __syncthreads();
        if (tid < PNL) {
            float mv = red[tid];
#pragma unroll
            for (int w = 1; w < 8; ++w) mv = fminf(mv, red[w * PNL + tid]);
            float y2g = y2[(size_t)bz * NPAD + tP * PNL + tid];
            row_min[(size_t)bz * NPAD + tP * PNL + tid] =
                fmaxf(y2g + mv, 0.f) * (1.0f / (float)DDIM);
        }
    } else {
        // reduce over stream rows -> cross-wave -> clamp/mask -> 1 atomic
#pragma unroll
        for (int nb = 0; nb < 4; ++nb) {
            float v = runmin[nb];
            v = fminf(v, __shfl_xor(v, 16));
            v = fminf(v, __shfl_xor(v, 32));
            if (lane < 16) red[wid * PNL + nb * 16 + lane] = v;
        }
        __syncthreads();
        if (tid < PNL) {
            int gc = tP * PNL + tid;
            float cv = red[tid];
#pragma unroll
            for (int w = 1; w < 8; ++w) cv = fminf(cv, red[w * PNL + tid]);
            cv = fmaxf(cv, 0.f);                   // deferred clamp (monotone)
            float s = (gc < NPAT) ? cv : 0.f;      // mask pad cols
            for (int o = 32; o; o >>= 1) s += __shfl_down(s, o);
            if (tid == 0)
                atomicAdd(out, s * (1.0f / (float)(BATCH * NPAT)));
        }
    }
}

extern "C" void kernel_launch(void* const* d_in, const int* in_sizes, int n_in,
                              void* d_out, int out_size, void* d_ws, size_t ws_size,
                              hipStream_t stream) {
    const float* x = (const float*)d_in[0];
    const float* y = (const float*)d_in[1];
    float* out = (float*)d_out;

    char* ws = (char*)d_ws;
    size_t patSz = (size_t)BATCH * NPAD * KPAD * sizeof(__hip_bfloat16); // 10.5 MB
    __hip_bfloat16* Xp = (__hip_bfloat16*)ws;
    __hip_bfloat16* Yp = (__hip_bfloat16*)(ws + patSz);
    float* x2 = (float*)(ws + 2 * patSz);
    float* y2 = x2 + BATCH * NPAD;
    float* row_min = y2 + BATCH * NPAD;
    float2* yr = (float2*)(row_min + BATCH * NPAD);

    dim3 eg(NPAD / 4, BATCH);
    extract_patches<<<eg, 256, 0, stream>>>(x, Xp, x2, out);   // zeroes out
    extract_patches<<<eg, 256, 0, stream>>>(y, Yp, y2, nullptr);

    int nblk = (NPAD / PNL) * BATCH;    // 512 blocks -> 2 per CU (grid-limited)
    panel_pass<1><<<nblk, 512, 0, stream>>>(Xp, Yp, x2, y2, yr, row_min, out);
    prep_rms<<<(BATCH * NPAD) / 256, 256, 0, stream>>>(row_min, y2, yr);
    panel_pass<2><<<nblk, 512, 0, stream>>>(Xp, Yp, x2, y2, yr, row_min, out);
}

// Round 15
// 210.102 us; speedup vs baseline: 1.2288x; 1.0715x over previous
//
#include <hip/hip_runtime.h>
#include <hip/hip_bf16.h>
#include <stdint.h>

#define IMG_H 96
#define IMG_W 96
#define IMG_C 3
#define HO    90                 // 96-7+1
#define NPAT  8100               // 90*90
#define NPAD  8192
#define DDIM  147                // 3*7*7
#define KPAD  160                // padded K (5 chunks of 32)
#define NCHK  5
#define BATCH 4
#define PNL   64                 // panel rows per block
#define SRT   128                // stream rows per tile
#define NT    (NPAD / SRT)       // 64 stream tiles
#define ALPHA 0.05f
#define QE    3072               // queue slot elems: 5*512 frag + 512 scalar

typedef __attribute__((ext_vector_type(8))) short short8;
typedef __attribute__((ext_vector_type(4))) float f32x4;

__device__ __forceinline__ void async16(const void* g, void* l) {
    __builtin_amdgcn_global_load_lds(
        (const __attribute__((address_space(1))) unsigned int*)g,
        (__attribute__((address_space(3))) unsigned int*)l,
        16, 0, 0);
}

// ---------- patch extraction + squared norms (+ out zero) ----------
__global__ __launch_bounds__(256) void extract_patches(
    const float* __restrict__ img,          // [B][3][96][96]
    __hip_bfloat16* __restrict__ pat,       // [B][NPAD][KPAD]
    float* __restrict__ nrm,                // [B][NPAD]
    float* __restrict__ outzero)            // may be null
{
    int wid  = threadIdx.x >> 6;
    int lane = threadIdx.x & 63;
    int pidx = blockIdx.x * 4 + wid;        // 0..8191
    int b    = blockIdx.y;
    if (pidx >= NPAD) return;
    if (outzero && blockIdx.x == 0 && blockIdx.y == 0 && threadIdx.x == 0)
        outzero[0] = 0.f;
    const float* im = img + (size_t)b * (IMG_C * IMG_H * IMG_W);
    __hip_bfloat16* pp = pat + ((size_t)b * NPAD + pidx) * KPAD;
    int r = pidx / HO, c = pidx - r * HO;
    bool valid = pidx < NPAT;
    float ss = 0.f;
    for (int d = lane; d < KPAD; d += 64) {
        float v = 0.f;
        if (valid && d < DDIM) {
            int ch  = d / 49;
            int rem = d - ch * 49;
            int pr  = rem / 7, pc = rem - pr * 7;
            v = im[ch * (IMG_H * IMG_W) + (r + pr) * IMG_W + (c + pc)];
        }
        pp[d] = __float2bfloat16(v);
        ss += v * v;
    }
    for (int s = 32; s; s >>= 1) ss += __shfl_down(ss, s);
    if (lane == 0) nrm[(size_t)b * NPAD + pidx] = ss;
}

// ---------- prep: (y2, rms) float2; rms = invD/(row_min+a), inf on pads ----------
__global__ __launch_bounds__(256) void prep_rms(
    const float* __restrict__ row_min, const float* __restrict__ y2,
    float2* __restrict__ yr)
{
    int i = blockIdx.x * 256 + threadIdx.x;
    if (i < BATCH * NPAD) {
        int j = i & (NPAD - 1);
        float rm = row_min[i];
        float rr = (j < NPAT) ? (1.0f / (float)DDIM) / (rm + ALPHA)
                              : __builtin_inff();
        yr[i] = make_float2(y2[i], rr);
    }
}

// ------------- panel-persistent, per-wave async 3-deep LDS queue -------------
// 512 blocks x 512 threads. Panel (64 rows) in p_reg[5][4]. Each wave owns a
// PRIVATE 3-slot LDS queue for its 16-row stream slice + per-tile scalars
// (6 async16/tile). NO barriers in the loop: per-wave s_waitcnt vmcnt only.
// Steady state 18 VMEM in flight/wave -> L2-BW-bound, latency amortized.
// Slot reuse (distance 3) guarded by lgkmcnt(0) after each tile's LDS reads.
// PASS 1: row-min in regs -> plain store per panel row. PASS 2: col-min ->
// one atomicAdd partial per block. fmin order-invariant -> exact.
template <int PASS>
__global__ __launch_bounds__(512, 2) void panel_pass(
    const __hip_bfloat16* __restrict__ Xp,   // [B][NPAD][KPAD]
    const __hip_bfloat16* __restrict__ Yp,   // [B][NPAD][KPAD]
    const float* __restrict__ x2,
    const float* __restrict__ y2,
    const float2* __restrict__ yr,           // PASS2: (y2, rms) pairs
    float* __restrict__ row_min,
    float* __restrict__ out)                 // PASS2 only
{
    __shared__ __align__(16) __hip_bfloat16 Q[8][3][QE];   // 147456 B

    int blk = blockIdx.x;
    int bz  = blk & 3;               // image: fixed per XCD under %8 rr
    int tP  = blk >> 2;              // panel index 0..127
    int tid = threadIdx.x;
    int wid = tid >> 6, lane = tid & 63;
    int fr  = lane & 15;
    int koq = lane >> 4;             // k-quad 0..3

    const __hip_bfloat16* Pbase =
        (PASS == 1 ? Yp : Xp) + ((size_t)bz * NPAD + tP * PNL) * KPAD;
    const __hip_bfloat16* Sbase =
        (PASS == 1 ? Xp : Yp) + (size_t)bz * NPAD * KPAD;
    const float*  sx2 = x2 + (size_t)bz * NPAD;
    const float2* syr = yr + (size_t)bz * NPAD;

    int srW  = wid * 16;             // wave's stream slice base row
    int slog = (lane & 3) ^ (((lane >> 2) >> 1) & 3);   // store swizzle

    // stage tile t's 16-row slice + scalars into own queue slot (6 async16)
    auto stage = [&](int slot, int t) {
        const __hip_bfloat16* src = Sbase +
            ((size_t)t * SRT + srW + (lane >> 2)) * KPAD + slog * 8;
        __hip_bfloat16* dst = &Q[wid][slot][0];
        for (int c = 0; c < NCHK; ++c)
            async16(src + c * 32, dst + c * 512);
        if (PASS == 1) {
            int l = lane < 4 ? lane : 3;   // clamp: dup writes land in pad
            async16(sx2 + (size_t)t * SRT + srW + l * 4, dst + 2560);
        } else {
            int l = lane < 8 ? lane : 7;
            async16(syr + (size_t)t * SRT + srW + l * 2, dst + 2560);
        }
    };

    // ---- panel stage (waves 0-3) into Q[0..3][0]; p_reg load; then free ----
    if (wid < 4) {
        const __hip_bfloat16* src = Pbase +
            ((size_t)(wid * 16 + (lane >> 2))) * KPAD + slog * 8;
        __hip_bfloat16* dst = &Q[wid][0][0];
        for (int c = 0; c < NCHK; ++c)
            async16(src + c * 32, dst + c * 512);
    }
    __syncthreads();                 // panel landed (vmcnt drained)

    int sread = (koq ^ ((fr >> 1) & 3)) * 8;            // read swizzle
    short8 p_reg[NCHK][4];
#pragma unroll
    for (int c = 0; c < NCHK; ++c)
#pragma unroll
        for (int m = 0; m < 4; ++m)
            p_reg[c][m] = *(const short8*)&Q[m][0][c * 512 + fr * 32 + sread];

    float xv[4];   // PASS2: panel cols' x2 (direct global, once)
    if (PASS == 2)
#pragma unroll
        for (int nb = 0; nb < 4; ++nb)
            xv[nb] = x2[(size_t)bz * NPAD + tP * PNL + nb * 16 + fr];

    __syncthreads();                 // everyone past panel reads; Q reusable

    float runmin[PASS == 1 ? 16 : 4];
#pragma unroll
    for (int i = 0; i < (PASS == 1 ? 16 : 4); ++i)
        runmin[i] = __builtin_inff();

    // compute one tile from queue slot; drain LDS reads before slot reuse
    auto body = [&](int t, int slot) {
        const __hip_bfloat16* Sc = &Q[wid][slot][0];
        short8 f[NCHK];
#pragma unroll
        for (int c = 0; c < NCHK; ++c)
            f[c] = *(const short8*)&Sc[c * 512 + fr * 32 + sread];

        float xg = 0.f;
        float2 pq[4];
        if (PASS == 1) {
            xg = ((const float*)&Sc[2560])[fr];
            if (t * SRT + srW + fr >= NPAT) xg = __builtin_inff();
        } else {
#pragma unroll
            for (int reg = 0; reg < 4; ++reg)
                pq[reg] = ((const float2*)&Sc[2560])[koq * 4 + reg];
        }

        f32x4 acc[4] = {};
#pragma unroll
        for (int c = 0; c < NCHK; ++c) {
            if (PASS == 1) {
#pragma unroll
                for (int m = 0; m < 4; ++m)
                    acc[m] = __builtin_amdgcn_mfma_f32_16x16x32_bf16(
                        p_reg[c][m], f[c], acc[m], 0, 0, 0);
            } else {
#pragma unroll
                for (int nb = 0; nb < 4; ++nb)
                    acc[nb] = __builtin_amdgcn_mfma_f32_16x16x32_bf16(
                        f[c], p_reg[c][nb], acc[nb], 0, 0, 0);
            }
        }

        if (PASS == 1) {
#pragma unroll
            for (int m = 0; m < 4; ++m)
#pragma unroll
                for (int reg = 0; reg < 4; ++reg)
                    runmin[m * 4 + reg] = fminf(runmin[m * 4 + reg],
                        fmaf(-2.0f, acc[m][reg], xg));
        } else {
#pragma unroll
            for (int reg = 0; reg < 4; ++reg) {
                float yv = pq[reg].x, rr = pq[reg].y;   // rr=inf on pad rows
#pragma unroll
                for (int nb = 0; nb < 4; ++nb)
                    runmin[nb] = fminf(runmin[nb],
                        fmaf(-2.0f, acc[nb][reg], yv + xv[nb]) * rr);
            }
        }
        // all this slot's LDS reads returned -> safe to overwrite afterwards
        asm volatile("s_waitcnt lgkmcnt(0)" ::: "memory");
    };

    // prologue: 3 tiles in flight (18 VMEM/wave)
    stage(0, 0);
    stage(1, 1);
    stage(2, 2);

#pragma unroll 1
    for (int t = 0; t <= NT - 3; ++t) {          // t = 0..61
        asm volatile("s_waitcnt vmcnt(12)" ::: "memory");  // tile t landed
        body(t, t % 3);
        if (t + 3 < NT) stage(t % 3, t + 3);     // refill freed slot
    }
    asm volatile("s_waitcnt vmcnt(6)" ::: "memory");
    body(NT - 2, (NT - 2) % 3);
    asm volatile("s_waitcnt vmcnt(0)" ::: "memory");
    body(NT - 1, (NT - 1) % 3);

    // ---- epilogue: red[] aliases queue (dead) ----
    __syncthreads();
    float* red = (float*)&Q[0][0][0];            // [8][PNL]

    if (PASS == 1) {
#pragma unroll
        for (int m = 0; m < 4; ++m)
#pragma unroll
            for (int reg = 0; reg < 4; ++reg) {
                float v = runmin[m * 4 + reg];
                for (int s = 1; s < 16; s <<= 1)
                    v = fminf(v, __shfl_xor(v, s));
                if (fr == 0)
                    red[wid * PNL + m * 16 + koq * 4 + reg] = v;
            }
        __syncthreads();
        if (tid < PNL) {
            float mv = red[tid];
#pragma unroll
            for (int w = 1; w < 8; ++w) mv = fminf(mv, red[w * PNL + tid]);
            float y2g = y2[(size_t)bz * NPAD + tP * PNL + tid];
            row_min[(size_t)bz * NPAD + tP * PNL + tid] =
                fmaxf(y2g + mv, 0.f) * (1.0f / (float)DDIM);
        }
    } else {
#pragma unroll
        for (int nb = 0; nb < 4; ++nb) {
            float v = runmin[nb];
            v = fminf(v, __shfl_xor(v, 16));
            v = fminf(v, __shfl_xor(v, 32));
            if (lane < 16) red[wid * PNL + nb * 16 + lane] = v;
        }
        __syncthreads();
        if (tid < PNL) {
            int gc = tP * PNL + tid;
            float cv = red[tid];
#pragma unroll
            for (int w = 1; w < 8; ++w) cv = fminf(cv, red[w * PNL + tid]);
            cv = fmaxf(cv, 0.f);                   // deferred clamp (monotone)
            float s = (gc < NPAT) ? cv : 0.f;      // mask pad cols
            for (int o = 32; o; o >>= 1) s += __shfl_down(s, o);
            if (tid == 0)
                atomicAdd(out, s * (1.0f / (float)(BATCH * NPAT)));
        }
    }
}

extern "C" void kernel_launch(void* const* d_in, const int* in_sizes, int n_in,
                              void* d_out, int out_size, void* d_ws, size_t ws_size,
                              hipStream_t stream) {
    const float* x = (const float*)d_in[0];
    const float* y = (const float*)d_in[1];
    float* out = (float*)d_out;

    char* ws = (char*)d_ws;
    size_t patSz = (size_t)BATCH * NPAD * KPAD * sizeof(__hip_bfloat16); // 10.5 MB
    __hip_bfloat16* Xp = (__hip_bfloat16*)ws;
    __hip_bfloat16* Yp = (__hip_bfloat16*)(ws + patSz);
    float* x2 = (float*)(ws + 2 * patSz);
    float* y2 = x2 + BATCH * NPAD;
    float* row_min = y2 + BATCH * NPAD;
    float2* yr = (float2*)(row_min + BATCH * NPAD);

    dim3 eg(NPAD / 4, BATCH);
    extract_patches<<<eg, 256, 0, stream>>>(x, Xp, x2, out);   // zeroes out
    extract_patches<<<eg, 256, 0, stream>>>(y, Yp, y2, nullptr);

    int nblk = (NPAD / PNL) * BATCH;    // 512 blocks
    panel_pass<1><<<nblk, 512, 0, stream>>>(Xp, Yp, x2, y2, yr, row_min, out);
    prep_rms<<<(BATCH * NPAD) / 256, 256, 0, stream>>>(row_min, y2, yr);
    panel_pass<2><<<nblk, 512, 0, stream>>>(Xp, Yp, x2, y2, yr, row_min, out);
}

// Round 16
// 199.621 us; speedup vs baseline: 1.2933x; 1.0525x over previous
//
#include <hip/hip_runtime.h>
#include <hip/hip_bf16.h>
#include <stdint.h>

#define IMG_H 96
#define IMG_W 96
#define IMG_C 3
#define HO    90                 // 96-7+1
#define NPAT  8100               // 90*90
#define NPAD  8192
#define DDIM  147                // 3*7*7
#define KPAD  160                // padded K (5 chunks of 32)
#define NCHK  5
#define BATCH 4
#define PNL   64                 // panel rows per block
#define SRT   128                // stream rows per tile
#define NT    (NPAD / SRT)       // 64 stream tiles
#define ALPHA 0.05f
#define QE    3072               // queue slot elems: 5*512 frag + 512 scalar

typedef __attribute__((ext_vector_type(8))) short short8;
typedef __attribute__((ext_vector_type(4))) float f32x4;

__device__ __forceinline__ void async16(const void* g, void* l) {
    __builtin_amdgcn_global_load_lds(
        (const __attribute__((address_space(1))) unsigned int*)g,
        (__attribute__((address_space(3))) unsigned int*)l,
        16, 0, 0);
}

// ---------- patch extraction + squared norms (+ out zero) ----------
__global__ __launch_bounds__(256) void extract_patches(
    const float* __restrict__ img,          // [B][3][96][96]
    __hip_bfloat16* __restrict__ pat,       // [B][NPAD][KPAD]
    float* __restrict__ nrm,                // [B][NPAD]
    float* __restrict__ outzero)            // may be null
{
    int wid  = threadIdx.x >> 6;
    int lane = threadIdx.x & 63;
    int pidx = blockIdx.x * 4 + wid;        // 0..8191
    int b    = blockIdx.y;
    if (pidx >= NPAD) return;
    if (outzero && blockIdx.x == 0 && blockIdx.y == 0 && threadIdx.x == 0)
        outzero[0] = 0.f;
    const float* im = img + (size_t)b * (IMG_C * IMG_H * IMG_W);
    __hip_bfloat16* pp = pat + ((size_t)b * NPAD + pidx) * KPAD;
    int r = pidx / HO, c = pidx - r * HO;
    bool valid = pidx < NPAT;
    float ss = 0.f;
    for (int d = lane; d < KPAD; d += 64) {
        float v = 0.f;
        if (valid && d < DDIM) {
            int ch  = d / 49;
            int rem = d - ch * 49;
            int pr  = rem / 7, pc = rem - pr * 7;
            v = im[ch * (IMG_H * IMG_W) + (r + pr) * IMG_W + (c + pc)];
        }
        pp[d] = __float2bfloat16(v);
        ss += v * v;
    }
    for (int s = 32; s; s >>= 1) ss += __shfl_down(ss, s);
    if (lane == 0) nrm[(size_t)b * NPAD + pidx] = ss;
}

// ---------- prep: (y2, rms) float2; rms = invD/(row_min+a), inf on pads ----------
__global__ __launch_bounds__(256) void prep_rms(
    const float* __restrict__ row_min, const float* __restrict__ y2,
    float2* __restrict__ yr)
{
    int i = blockIdx.x * 256 + threadIdx.x;
    if (i < BATCH * NPAD) {
        int j = i & (NPAD - 1);
        float rm = row_min[i];
        float rr = (j < NPAT) ? (1.0f / (float)DDIM) / (rm + ALPHA)
                              : __builtin_inff();
        yr[i] = make_float2(y2[i], rr);
    }
}

// ------------- panel-persistent, per-wave async 3-deep LDS queue -------------
// R15 structure (97 us/pass, verified) with address-VALU eliminated:
//  - loop unrolled by 3 -> queue slot is a LITERAL -> ds_read = one per-lane
//    base VGPR + immediate offsets (slot*6144B + c*1024B, 16-bit imm)
//  - staging via monotone running pointers += SRT*KPAD (no per-tile 64-bit
//    address rebuild, no %3 magic-multiply); chunk offsets are 13-bit imms
//  - exact vmcnt literals: steady 12, tail 12/6/0 (6 VMEM per staged tile)
template <int PASS>
__global__ __launch_bounds__(512, 2) void panel_pass(
    const __hip_bfloat16* __restrict__ Xp,   // [B][NPAD][KPAD]
    const __hip_bfloat16* __restrict__ Yp,   // [B][NPAD][KPAD]
    const float* __restrict__ x2,
    const float* __restrict__ y2,
    const float2* __restrict__ yr,           // PASS2: (y2, rms) pairs
    float* __restrict__ row_min,
    float* __restrict__ out)                 // PASS2 only
{
    __shared__ __align__(16) __hip_bfloat16 Q[8][3][QE];   // 147456 B

    int blk = blockIdx.x;
    int bz  = blk & 3;               // image: fixed per XCD under %8 rr
    int tP  = blk >> 2;              // panel index 0..127
    int tid = threadIdx.x;
    int wid = tid >> 6, lane = tid & 63;
    int fr  = lane & 15;
    int koq = lane >> 4;             // k-quad 0..3

    const __hip_bfloat16* Pbase =
        (PASS == 1 ? Yp : Xp) + ((size_t)bz * NPAD + tP * PNL) * KPAD;
    const __hip_bfloat16* Sbase =
        (PASS == 1 ? Xp : Yp) + (size_t)bz * NPAD * KPAD;
    const float*  sx2 = x2 + (size_t)bz * NPAD;
    const float2* syr = yr + (size_t)bz * NPAD;

    int srW  = wid * 16;             // wave's stream slice base row
    int slog = (lane & 3) ^ (((lane >> 2) >> 1) & 3);   // store swizzle

    // ---- panel stage (waves 0-3) into Q[0..3][0]; p_reg load; then free ----
    if (wid < 4) {
        const __hip_bfloat16* src = Pbase +
            ((size_t)(wid * 16 + (lane >> 2))) * KPAD + slog * 8;
        __hip_bfloat16* dst = &Q[wid][0][0];
        for (int c = 0; c < NCHK; ++c)
            async16(src + c * 32, dst + c * 512);
    }
    __syncthreads();                 // panel landed (vmcnt drained)

    int sread = (koq ^ ((fr >> 1) & 3)) * 8;            // read swizzle
    short8 p_reg[NCHK][4];
#pragma unroll
    for (int c = 0; c < NCHK; ++c)
#pragma unroll
        for (int m = 0; m < 4; ++m)
            p_reg[c][m] = *(const short8*)&Q[m][0][c * 512 + fr * 32 + sread];

    float xv[4];   // PASS2: panel cols' x2 (direct global, once)
    if (PASS == 2)
#pragma unroll
        for (int nb = 0; nb < 4; ++nb)
            xv[nb] = x2[(size_t)bz * NPAD + tP * PNL + nb * 16 + fr];

    __syncthreads();                 // everyone past panel reads; Q reusable

    float runmin[PASS == 1 ? 16 : 4];
#pragma unroll
    for (int i = 0; i < (PASS == 1 ? 16 : 4); ++i)
        runmin[i] = __builtin_inff();

    // ---- fixed per-lane read bases (all queue reads = base + IMM) ----
    const __hip_bfloat16* qrd = &Q[wid][0][fr * 32 + sread]; // + s*3072 + c*512
    const float*  qs1 = (const float*)&Q[wid][0][2560];      // + s*1536 + fr
    const float2* qs2 = (const float2*)&Q[wid][0][2560];     // + s*768 + idx

    // ---- monotone staging pointers (+= const per staged tile) ----
    const __hip_bfloat16* sfrag =
        Sbase + (size_t)(srW + (lane >> 2)) * KPAD + slog * 8;
    const float*  ss1 = sx2 + srW + (lane < 4 ? lane : 3) * 4;
    const float2* ss2 = syr + srW + (lane < 8 ? lane : 7) * 2;

    auto stage = [&](int slot) {     // slot is a literal at every call site
        __hip_bfloat16* dst = &Q[wid][slot][0];
#pragma unroll
        for (int c = 0; c < NCHK; ++c)
            async16(sfrag + c * 32, dst + c * 512);
        if (PASS == 1) { async16(ss1, dst + 2560); ss1 += SRT; }
        else           { async16(ss2, dst + 2560); ss2 += SRT; }
        sfrag += (size_t)SRT * KPAD;
    };

    auto body = [&](int t, int slot) {   // slot literal -> imm addressing
        short8 f[NCHK];
#pragma unroll
        for (int c = 0; c < NCHK; ++c)
            f[c] = *(const short8*)(qrd + slot * QE + c * 512);

        float xg = 0.f;
        float2 pq[4];
        if (PASS == 1) {
            xg = qs1[slot * 1536 + fr];
            if (t * SRT + srW + fr >= NPAT) xg = __builtin_inff();
        } else {
#pragma unroll
            for (int reg = 0; reg < 4; ++reg)
                pq[reg] = qs2[slot * 768 + koq * 4 + reg];
        }

        f32x4 acc[4] = {};
#pragma unroll
        for (int c = 0; c < NCHK; ++c) {
            if (PASS == 1) {
#pragma unroll
                for (int m = 0; m < 4; ++m)
                    acc[m] = __builtin_amdgcn_mfma_f32_16x16x32_bf16(
                        p_reg[c][m], f[c], acc[m], 0, 0, 0);
            } else {
#pragma unroll
                for (int nb = 0; nb < 4; ++nb)
                    acc[nb] = __builtin_amdgcn_mfma_f32_16x16x32_bf16(
                        f[c], p_reg[c][nb], acc[nb], 0, 0, 0);
            }
        }

        if (PASS == 1) {
#pragma unroll
            for (int m = 0; m < 4; ++m)
#pragma unroll
                for (int reg = 0; reg < 4; ++reg)
                    runmin[m * 4 + reg] = fminf(runmin[m * 4 + reg],
                        fmaf(-2.0f, acc[m][reg], xg));
        } else {
#pragma unroll
            for (int reg = 0; reg < 4; ++reg) {
                float yv = pq[reg].x, rr = pq[reg].y;   // rr=inf on pad rows
#pragma unroll
                for (int nb = 0; nb < 4; ++nb)
                    runmin[nb] = fminf(runmin[nb],
                        fmaf(-2.0f, acc[nb][reg], yv + xv[nb]) * rr);
            }
        }
        // this slot's LDS reads returned -> safe to overwrite afterwards
        asm volatile("s_waitcnt lgkmcnt(0)" ::: "memory");
    };

#define W12 asm volatile("s_waitcnt vmcnt(12)" ::: "memory")
    // prologue: 3 tiles in flight (18 VMEM/wave)
    stage(0); stage(1); stage(2);    // tiles 0,1,2

    int t = 0;
#pragma unroll 1
    for (int tt = 0; tt < 19; ++tt) {   // bodies t=0..56, stages tiles 3..59
        W12; body(t, 0); stage(0);
        W12; body(t + 1, 1); stage(1);
        W12; body(t + 2, 2); stage(2);
        t += 3;
    }
    // tail: bodies 57..63, stages tiles 60..63 (slot == tile%3 throughout)
    W12; body(57, 0); stage(0);      // tile 60
    W12; body(58, 1); stage(1);      // tile 61
    W12; body(59, 2); stage(2);      // tile 62
    W12; body(60, 0); stage(0);      // tile 63
    W12; body(61, 1);
    asm volatile("s_waitcnt vmcnt(6)" ::: "memory"); body(62, 2);
    asm volatile("s_waitcnt vmcnt(0)" ::: "memory"); body(63, 0);
#undef W12

    // ---- epilogue: red[] aliases queue (dead) ----
    __syncthreads();
    float* red = (float*)&Q[0][0][0];            // [8][PNL]

    if (PASS == 1) {
#pragma unroll
        for (int m = 0; m < 4; ++m)
#pragma unroll
            for (int reg = 0; reg < 4; ++reg) {
                float v = runmin[m * 4 + reg];
                for (int s = 1; s < 16; s <<= 1)
                    v = fminf(v, __shfl_xor(v, s));
                if (fr == 0)
                    red[wid * PNL + m * 16 + koq * 4 + reg] = v;
            }
        __syncthreads();
        if (tid < PNL) {
            float mv = red[tid];
#pragma unroll
            for (int w = 1; w < 8; ++w) mv = fminf(mv, red[w * PNL + tid]);
            float y2g = y2[(size_t)bz * NPAD + tP * PNL + tid];
            row_min[(size_t)bz * NPAD + tP * PNL + tid] =
                fmaxf(y2g + mv, 0.f) * (1.0f / (float)DDIM);
        }
    } else {
#pragma unroll
        for (int nb = 0; nb < 4; ++nb) {
            float v = runmin[nb];
            v = fminf(v, __shfl_xor(v, 16));
            v = fminf(v, __shfl_xor(v, 32));
            if (lane < 16) red[wid * PNL + nb * 16 + lane] = v;
        }
        __syncthreads();
        if (tid < PNL) {
            int gc = tP * PNL + tid;
            float cv = red[tid];
#pragma unroll
            for (int w = 1; w < 8; ++w) cv = fminf(cv, red[w * PNL + tid]);
            cv = fmaxf(cv, 0.f);                   // deferred clamp (monotone)
            float s = (gc < NPAT) ? cv : 0.f;      // mask pad cols
            for (int o = 32; o; o >>= 1) s += __shfl_down(s, o);
            if (tid == 0)
                atomicAdd(out, s * (1.0f / (float)(BATCH * NPAT)));
        }
    }
}

extern "C" void kernel_launch(void* const* d_in, const int* in_sizes, int n_in,
                              void* d_out, int out_size, void* d_ws, size_t ws_size,
                              hipStream_t stream) {
    const float* x = (const float*)d_in[0];
    const float* y = (const float*)d_in[1];
    float* out = (float*)d_out;

    char* ws = (char*)d_ws;
    size_t patSz = (size_t)BATCH * NPAD * KPAD * sizeof(__hip_bfloat16); // 10.5 MB
    __hip_bfloat16* Xp = (__hip_bfloat16*)ws;
    __hip_bfloat16* Yp = (__hip_bfloat16*)(ws + patSz);
    float* x2 = (float*)(ws + 2 * patSz);
    float* y2 = x2 + BATCH * NPAD;
    float* row_min = y2 + BATCH * NPAD;
    float2* yr = (float2*)(row_min + BATCH * NPAD);

    dim3 eg(NPAD / 4, BATCH);
    extract_patches<<<eg, 256, 0, stream>>>(x, Xp, x2, out);   // zeroes out
    extract_patches<<<eg, 256, 0, stream>>>(y, Yp, y2, nullptr);

    int nblk = (NPAD / PNL) * BATCH;    // 512 blocks
    panel_pass<1><<<nblk, 512, 0, stream>>>(Xp, Yp, x2, y2, yr, row_min, out);
    prep_rms<<<(BATCH * NPAD) / 256, 256, 0, stream>>>(row_min, y2, yr);
    panel_pass<2><<<nblk, 512, 0, stream>>>(Xp, Yp, x2, y2, yr, row_min, out);
}